// Round 1
// baseline (355.117 us; speedup 1.0000x reference)
//
#include <hip/hip_runtime.h>
#include <stdint.h>

// BinaryLinear: out[8192,4096] = x[8192,4096] @ W[4096,4096]^T + sign(bias)
// W, bias are already {-1,+1}; binarize(0)->+1 handled via (v>=0).
// Strategy: pre-convert x->bf16 and W->bf16(+/-1) into d_ws, then m97-style
// 128x128 bf16 MFMA GEMM (gemm_bt: both operands row-major over K).

#define M_DIM 8192
#define N_DIM 4096
#define K_DIM 4096

typedef unsigned short ushort_t;
typedef __bf16 bf16x8 __attribute__((ext_vector_type(8)));
typedef float  f32x4  __attribute__((ext_vector_type(4)));
typedef ushort_t ushort4v __attribute__((ext_vector_type(4)));
typedef ushort_t ushort8v __attribute__((ext_vector_type(8)));

static __device__ __forceinline__ ushort_t f32_to_bf16_rne(float f) {
    unsigned u = __builtin_bit_cast(unsigned, f);
    unsigned r = 0x7FFFu + ((u >> 16) & 1u);   // round-to-nearest-even
    return (ushort_t)((u + r) >> 16);
}

// ---- conversion kernels (memory-bound, fully coalesced 16B/8B per lane) ----

__global__ __launch_bounds__(256) void cvt_x_kernel(const float* __restrict__ x,
                                                    ushort_t* __restrict__ xb) {
    size_t i = ((size_t)blockIdx.x * 256 + threadIdx.x) * 4;
    float4 v = *reinterpret_cast<const float4*>(x + i);
    ushort4v o;
    o.x = f32_to_bf16_rne(v.x);
    o.y = f32_to_bf16_rne(v.y);
    o.z = f32_to_bf16_rne(v.z);
    o.w = f32_to_bf16_rne(v.w);
    *reinterpret_cast<ushort4v*>(xb + i) = o;
}

__global__ __launch_bounds__(256) void cvt_w_kernel(const float* __restrict__ w,
                                                    ushort_t* __restrict__ wb) {
    size_t i = ((size_t)blockIdx.x * 256 + threadIdx.x) * 4;
    float4 v = *reinterpret_cast<const float4*>(w + i);
    ushort4v o;  // binarize: >=0 -> +1.0bf16, else -1.0bf16
    o.x = (v.x >= 0.f) ? 0x3F80u : 0xBF80u;
    o.y = (v.y >= 0.f) ? 0x3F80u : 0xBF80u;
    o.z = (v.z >= 0.f) ? 0x3F80u : 0xBF80u;
    o.w = (v.w >= 0.f) ? 0x3F80u : 0xBF80u;
    *reinterpret_cast<ushort4v*>(wb + i) = o;
}

// ---- GEMM: C[m,n] = sum_k A[m,k]*B[n,k] + sign(bias[n]) ----
// 128x128 tile, BK=32, 256 threads = 4 waves in 2x2, each wave 64x64 out.

static __device__ __forceinline__ void gload_lds16(const void* g, void* s) {
    __builtin_amdgcn_global_load_lds(
        (const __attribute__((address_space(1))) void*)(g),
        (__attribute__((address_space(3))) void*)(s),
        16, 0, 0);
}

__global__ __launch_bounds__(256) void bgemm_kernel(const ushort_t* __restrict__ A,
                                                    const ushort_t* __restrict__ Bm,
                                                    const float* __restrict__ bias,
                                                    float* __restrict__ C) {
    __shared__ ushort_t As[128 * 32];
    __shared__ ushort_t Bs[128 * 32];

    const int t = threadIdx.x;
    const int w = t >> 6;      // wave id 0..3
    const int l = t & 63;      // lane

    // XCD-aware swizzle: 2048 blocks, 2048 % 8 == 0 -> simple swizzle bijective
    const int bid = blockIdx.x;
    const int wg  = (bid & 7) * 256 + (bid >> 3);
    const int tn  = wg & 31;   // 32 col tiles (N=4096/128)
    const int tm  = wg >> 5;   // 64 row tiles (M=8192/128)

    // ---- staging addressing (global_load_lds: wave-uniform LDS base + lane*16B)
    // tile = 512 chunks of 16B; chunk q -> row q>>2, kcol (q&3)*8 elems.
    // wave w, call c covers chunks [c*256 + w*64, +64).
    const int srow = t >> 2;          // 0..63
    const int scol = (t & 3) * 8;     // k-element offset within BK
    const ushort_t* a_src0 = A  + (size_t)(tm * 128 + srow) * K_DIM + scol;
    const ushort_t* a_src1 = a_src0 + (size_t)64 * K_DIM;
    const ushort_t* b_src0 = Bm + (size_t)(tn * 128 + srow) * K_DIM + scol;
    const ushort_t* b_src1 = b_src0 + (size_t)64 * K_DIM;
    ushort_t* a_dst0 = &As[w * 512];          // (0*256 + w*64) chunks * 8 ushort
    ushort_t* a_dst1 = &As[2048 + w * 512];   // (1*256 + w*64) chunks * 8 ushort
    ushort_t* b_dst0 = &Bs[w * 512];
    ushort_t* b_dst1 = &Bs[2048 + w * 512];

    // ---- fragment addressing
    const int wr = w >> 1, wc = w & 1;     // wave 2x2 within tile
    const int lr = l & 15;                 // fragment row (A) / col (B)
    const int kh = l >> 4;                 // k-half group: k offset = kh*8
    const ushort_t* pa = &As[(wr * 64 + lr) * 32 + kh * 8];
    const ushort_t* pb = &Bs[(wc * 64 + lr) * 32 + kh * 8];

    f32x4 acc[4][4] = {};

    for (int kt = 0; kt < K_DIM / 32; ++kt) {
        const size_t ko = (size_t)kt * 32;
        gload_lds16(a_src0 + ko, a_dst0);
        gload_lds16(a_src1 + ko, a_dst1);
        gload_lds16(b_src0 + ko, b_dst0);
        gload_lds16(b_src1 + ko, b_dst1);
        __syncthreads();   // vmcnt(0) drain -> staged data visible

        bf16x8 af[4], bfr[4];
#pragma unroll
        for (int m = 0; m < 4; ++m)
            af[m] = *reinterpret_cast<const bf16x8*>(pa + m * 16 * 32);
#pragma unroll
        for (int n = 0; n < 4; ++n)
            bfr[n] = *reinterpret_cast<const bf16x8*>(pb + n * 16 * 32);
#pragma unroll
        for (int m = 0; m < 4; ++m)
#pragma unroll
            for (int n = 0; n < 4; ++n)
                acc[m][n] = __builtin_amdgcn_mfma_f32_16x16x32_bf16(
                    af[m], bfr[n], acc[m][n], 0, 0, 0);
        __syncthreads();   // all waves done reading before next stage
    }

    // ---- epilogue: C/D layout col=lane&15, row=(lane>>4)*4+reg (verified m91)
    const int col0 = tn * 128 + wc * 64 + lr;
    const int row0 = tm * 128 + wr * 64 + kh * 4;
    float bsgn[4];
#pragma unroll
    for (int n = 0; n < 4; ++n)
        bsgn[n] = (bias[col0 + n * 16] >= 0.f) ? 1.f : -1.f;
#pragma unroll
    for (int m = 0; m < 4; ++m) {
#pragma unroll
        for (int j = 0; j < 4; ++j) {
            float* crow = C + (size_t)(row0 + m * 16 + j) * N_DIM;
#pragma unroll
            for (int n = 0; n < 4; ++n)
                crow[col0 + n * 16] = acc[m][n][j] + bsgn[n];
        }
    }
}

extern "C" void kernel_launch(void* const* d_in, const int* in_sizes, int n_in,
                              void* d_out, int out_size, void* d_ws, size_t ws_size,
                              hipStream_t stream) {
    const float* x    = (const float*)d_in[0];
    const float* wgt  = (const float*)d_in[1];
    const float* bias = (const float*)d_in[2];
    float* out = (float*)d_out;

    // workspace: xb = 8192*4096 bf16 (64MB), wb = 4096*4096 bf16 (32MB)
    ushort_t* xb = (ushort_t*)d_ws;
    ushort_t* wb = xb + (size_t)M_DIM * K_DIM;

    cvt_x_kernel<<<(M_DIM * (size_t)K_DIM) / 4 / 256, 256, 0, stream>>>(x, xb);
    cvt_w_kernel<<<(N_DIM * (size_t)K_DIM) / 4 / 256, 256, 0, stream>>>(wgt, wb);

    dim3 grid((M_DIM / 128) * (N_DIM / 128));   // 64*32 = 2048 blocks
    bgemm_kernel<<<grid, 256, 0, stream>>>(xb, wb, bias, out);
}

// Round 3
// 282.809 us; speedup vs baseline: 1.2557x; 1.2557x over previous
//
#include <hip/hip_runtime.h>
#include <stdint.h>

// BinaryLinear: out[8192,4096] = x @ W^T + sign(bias); W,b in {-1,+1}.
// Round 3: 256x256 8-phase GEMM (T2 swizzle + T3/T4 counted vmcnt + T5
// setprio). Fix vs round 2: fragment column swizzle must XOR the FULL
// logical column (incl. kk*64) with ((row&7)<<4) — additive kk*64 outside
// the XOR carried into the row field for lanes with l&4 set.

#define M_DIM 8192
#define N_DIM 4096
#define K_DIM 4096
#define NKT   (K_DIM / 64)         // 64 K-tiles
#define KROW  ((size_t)K_DIM * 2)  // row bytes of bf16 operand = 8192

typedef unsigned short ushort_t;
typedef __bf16 bf16x8 __attribute__((ext_vector_type(8)));
typedef float  f32x4  __attribute__((ext_vector_type(4)));
typedef ushort_t ushort4v __attribute__((ext_vector_type(4)));

static __device__ __forceinline__ ushort_t f32_to_bf16_rne(float f) {
    unsigned u = __builtin_bit_cast(unsigned, f);
    unsigned r = 0x7FFFu + ((u >> 16) & 1u);
    return (ushort_t)((u + r) >> 16);
}

__global__ __launch_bounds__(256) void cvt_x_kernel(const float* __restrict__ x,
                                                    ushort_t* __restrict__ xb) {
    size_t i = ((size_t)blockIdx.x * 256 + threadIdx.x) * 4;
    float4 v = *reinterpret_cast<const float4*>(x + i);
    ushort4v o;
    o.x = f32_to_bf16_rne(v.x);
    o.y = f32_to_bf16_rne(v.y);
    o.z = f32_to_bf16_rne(v.z);
    o.w = f32_to_bf16_rne(v.w);
    *reinterpret_cast<ushort4v*>(xb + i) = o;
}

__global__ __launch_bounds__(256) void cvt_w_kernel(const float* __restrict__ w,
                                                    ushort_t* __restrict__ wb) {
    size_t i = ((size_t)blockIdx.x * 256 + threadIdx.x) * 4;
    float4 v = *reinterpret_cast<const float4*>(w + i);
    ushort4v o;
    o.x = (v.x >= 0.f) ? 0x3F80u : 0xBF80u;
    o.y = (v.y >= 0.f) ? 0x3F80u : 0xBF80u;
    o.z = (v.z >= 0.f) ? 0x3F80u : 0xBF80u;
    o.w = (v.w >= 0.f) ? 0x3F80u : 0xBF80u;
    *reinterpret_cast<ushort4v*>(wb + i) = o;
}

static __device__ __forceinline__ void gload_lds16(const void* g, void* s) {
    __builtin_amdgcn_global_load_lds(
        (const __attribute__((address_space(1))) void*)(g),
        (__attribute__((address_space(3))) void*)(s),
        16, 0, 0);
}

// LDS geometry: buf b at b*65536; A region +0 (32KB = 256 rows x 128B),
// B region +32768. Half h = rows h*128 = bytes [h*16384, +16384).
// Swizzle involution within region: P = L ^ (((L>>7)&7)<<4).

#define STAGE_A(bufbase, h, kt) do {                                        \
    char* _d = (bufbase) + (h)*16384 + w*1024;                              \
    gload_lds16(srcA0 + (size_t)(h)*1048576 + (size_t)(kt)*128, _d);        \
    gload_lds16(srcA1 + (size_t)(h)*1048576 + (size_t)(kt)*128, _d + 8192); \
} while (0)

#define STAGE_B(bufbase, h, kt) do {                                        \
    char* _d = (bufbase) + 32768 + (h)*16384 + w*1024;                      \
    gload_lds16(srcB0 + (size_t)(h)*1048576 + (size_t)(kt)*128, _d);        \
    gload_lds16(srcB1 + (size_t)(h)*1048576 + (size_t)(kt)*128, _d + 8192); \
} while (0)

#define LDA_FRAGS(Abase, Mh, areg) do {                                     \
    _Pragma("unroll") for (int m = 0; m < 4; ++m) {                         \
        areg[m*2+0] = *(const bf16x8*)((Abase) + pbA + (Mh)*16384           \
                                       + m*2048 + sxk0);                    \
        areg[m*2+1] = *(const bf16x8*)((Abase) + pbA + (Mh)*16384           \
                                       + m*2048 + sxk1);                    \
    }                                                                       \
} while (0)

#define LDB_FRAGS(Bbase, Nh, breg) do {                                     \
    _Pragma("unroll") for (int n = 0; n < 2; ++n) {                         \
        breg[n*2+0] = *(const bf16x8*)((Bbase) + pbB + (Nh)*16384           \
                                       + n*2048 + sxk0);                    \
        breg[n*2+1] = *(const bf16x8*)((Bbase) + pbB + (Nh)*16384           \
                                       + n*2048 + sxk1);                    \
    }                                                                       \
} while (0)

#define MM16(areg, breg, accq) do {                                         \
    __builtin_amdgcn_s_setprio(1);                                          \
    _Pragma("unroll") for (int m = 0; m < 4; ++m)                           \
    _Pragma("unroll") for (int n = 0; n < 2; ++n)                           \
    _Pragma("unroll") for (int kk = 0; kk < 2; ++kk)                        \
        accq[m][n] = __builtin_amdgcn_mfma_f32_16x16x32_bf16(               \
            areg[m*2+kk], breg[n*2+kk], accq[m][n], 0, 0, 0);               \
    __builtin_amdgcn_s_setprio(0);                                          \
} while (0)

#define WAIT_LGKM0() do {                                                   \
    asm volatile("s_waitcnt lgkmcnt(0)" ::: "memory");                      \
    __builtin_amdgcn_sched_barrier(0);                                      \
} while (0)

__global__ __launch_bounds__(512, 2)
void bgemm8_kernel(const ushort_t* __restrict__ A, const ushort_t* __restrict__ Bm,
                   const float* __restrict__ bias, float* __restrict__ C) {
    __shared__ char lds[131072];

    const int t = threadIdx.x;
    const int w = t >> 6;          // wave 0..7
    const int l = t & 63;
    const int wr = w >> 2;         // 0..1 (M)
    const int wc = w & 3;          // 0..3 (N)

    // XCD swizzle: 512 blocks, 512 % 8 == 0 -> bijective
    const int bid = blockIdx.x;
    const int wg  = (bid & 7) * 64 + (bid >> 3);
    const int tn  = wg & 15;       // N tiles: 4096/256 = 16
    const int tm  = wg >> 4;       // M tiles: 8192/256 = 32

    // ---- staging precompute: thread t, call j covers physical bytes
    // [(j*512+t)*16, +16) of a 16KB half-tile; invert swizzle for source.
    int srow[2], skb[2];
#pragma unroll
    for (int j = 0; j < 2; ++j) {
        int p = (j * 512 + t) * 16;
        int L = p ^ (((p >> 7) & 7) << 4);
        srow[j] = L >> 7;          // 0..127 row within half
        skb[j]  = L & 127;         // byte col within 128B row
    }
    const char* srcA0 = (const char*)A  + ((size_t)(tm * 256) + srow[0]) * KROW + skb[0];
    const char* srcA1 = (const char*)A  + ((size_t)(tm * 256) + srow[1]) * KROW + skb[1];
    const char* srcB0 = (const char*)Bm + ((size_t)(tn * 256) + srow[0]) * KROW + skb[0];
    const char* srcB1 = (const char*)Bm + ((size_t)(tn * 256) + srow[1]) * KROW + skb[1];

    // ---- fragment read addressing. Logical col (bytes) for K-subtile kk is
    // c = kk*64 + kh*16; physical = c ^ ((row&7)<<4), row&7 == l&7.
    const int lr = l & 15;
    const int kh = l >> 4;
    const int x7 = (l & 7) << 4;
    const int sxk0 = (kh * 16) ^ x7;
    const int sxk1 = (64 + kh * 16) ^ x7;
    const int pbA = (wr * 64 + lr) * 128;
    const int pbB = (wc * 32 + lr) * 128;

    // ---- prologue: tile0 all 4 halves -> buf0; tile1 A0,B0,A1 -> buf1
    {
        char* b0 = lds;
        char* b1 = lds + 65536;
        STAGE_A(b0, 0, 0); STAGE_B(b0, 0, 0); STAGE_A(b0, 1, 0); STAGE_B(b0, 1, 0);
        STAGE_A(b1, 0, 1); STAGE_B(b1, 0, 1); STAGE_A(b1, 1, 1);
    }
    asm volatile("s_waitcnt vmcnt(6)" ::: "memory");
    __builtin_amdgcn_s_barrier();

    f32x4 acc[2][2][4][2] = {};
    int cur = 0;

#pragma unroll 1
    for (int kt = 0; kt < NKT; ++kt) {
        char* curb = lds + cur * 65536;
        char* othb = lds + (cur ^ 1) * 65536;
        char* Ab = curb;
        char* Bb = curb + 32768;
        bf16x8 a[8], b0[4], b1[4];

        // ---- phase 1: quadrant (Mh0,Nh0); issue (kt+1).B1 -> other buf
        LDA_FRAGS(Ab, 0, a);
        LDB_FRAGS(Bb, 0, b0);
        if (kt + 1 < NKT) STAGE_B(othb, 1, kt + 1);
        __builtin_amdgcn_s_barrier();
        WAIT_LGKM0();
        MM16(a, b0, acc[0][0]);
        __builtin_amdgcn_s_barrier();

        // ---- phase 2: (Mh0,Nh1); issue (kt+2).A0 -> current buf (A0 dead)
        LDB_FRAGS(Bb, 1, b1);
        if (kt + 2 < NKT) STAGE_A(curb, 0, kt + 2);
        __builtin_amdgcn_s_barrier();
        WAIT_LGKM0();
        MM16(a, b1, acc[0][1]);
        __builtin_amdgcn_s_barrier();

        // ---- phase 3: (Mh1,Nh1); issue (kt+2).B0 -> current buf (B0 dead)
        LDA_FRAGS(Ab, 1, a);
        if (kt + 2 < NKT) STAGE_B(curb, 0, kt + 2);
        __builtin_amdgcn_s_barrier();
        WAIT_LGKM0();
        MM16(a, b1, acc[1][1]);
        __builtin_amdgcn_s_barrier();

        // ---- phase 4: (Mh1,Nh0); no ds_reads (a from ph3, b0 from ph1);
        //      issue (kt+2).A1 -> current buf (A1 dead after ph3)
        if (kt + 2 < NKT) STAGE_A(curb, 1, kt + 2);
        __builtin_amdgcn_s_barrier();
        MM16(a, b0, acc[1][0]);
        // ---- K-tile boundary: counted vmcnt, never 0 until epilogue
        if (kt + 2 < NKT)      asm volatile("s_waitcnt vmcnt(6)" ::: "memory");
        else if (kt + 1 < NKT) asm volatile("s_waitcnt vmcnt(0)" ::: "memory");
        __builtin_amdgcn_s_barrier();
        cur ^= 1;
    }

    // ---- epilogue: C/D layout col=lane&15, row=(lane>>4)*4+reg (verified)
    const int r0 = tm * 256 + wr * 64 + kh * 4;
    const int c0 = tn * 256 + wc * 32 + lr;
#pragma unroll
    for (int Mh = 0; Mh < 2; ++Mh)
#pragma unroll
    for (int Nh = 0; Nh < 2; ++Nh)
#pragma unroll
    for (int n = 0; n < 2; ++n) {
        const int col = c0 + Nh * 128 + n * 16;
        const float bs = (bias[col] >= 0.f) ? 1.f : -1.f;
#pragma unroll
        for (int m = 0; m < 4; ++m)
#pragma unroll
        for (int j = 0; j < 4; ++j) {
            const int row = r0 + Mh * 128 + m * 16 + j;
            C[(size_t)row * N_DIM + col] = acc[Mh][Nh][m][n][j] + bs;
        }
    }
}

extern "C" void kernel_launch(void* const* d_in, const int* in_sizes, int n_in,
                              void* d_out, int out_size, void* d_ws, size_t ws_size,
                              hipStream_t stream) {
    const float* x    = (const float*)d_in[0];
    const float* wgt  = (const float*)d_in[1];
    const float* bias = (const float*)d_in[2];
    float* out = (float*)d_out;

    ushort_t* xb = (ushort_t*)d_ws;                       // 64 MB
    ushort_t* wb = xb + (size_t)M_DIM * K_DIM;            // 32 MB

    cvt_x_kernel<<<(M_DIM * (size_t)K_DIM) / 4 / 256, 256, 0, stream>>>(x, xb);
    cvt_w_kernel<<<(N_DIM * (size_t)K_DIM) / 4 / 256, 256, 0, stream>>>(wgt, wb);

    dim3 grid((M_DIM / 256) * (N_DIM / 256));             // 32*16 = 512
    bgemm8_kernel<<<grid, 512, 0, stream>>>(xb, wb, bias, out);
}

// Round 4
// 275.136 us; speedup vs baseline: 1.2907x; 1.0279x over previous
//
#include <hip/hip_runtime.h>
#include <stdint.h>

// BinaryLinear: out[8192,4096] = x @ W^T + sign(bias); W,b in {-1,+1}.
// Round 4: same 256x256 8-phase schedule (passing, 0 bank conflicts) with
// three overlap fixes: (1) drop forced lgkmcnt(0) drains -> compiler emits
// progressive counted waits; (2) kk-outer MFMA order (independent chains);
// (3) unroll 2 K-tiles/iter -> static LDS bases, immediate-offset ds_reads.

#define M_DIM 8192
#define N_DIM 4096
#define K_DIM 4096
#define NKT   (K_DIM / 64)         // 64 K-tiles
#define KROW  ((size_t)K_DIM * 2)  // row bytes of bf16 operand = 8192

typedef unsigned short ushort_t;
typedef __bf16 bf16x8 __attribute__((ext_vector_type(8)));
typedef float  f32x4  __attribute__((ext_vector_type(4)));
typedef ushort_t ushort4v __attribute__((ext_vector_type(4)));

static __device__ __forceinline__ ushort_t f32_to_bf16_rne(float f) {
    unsigned u = __builtin_bit_cast(unsigned, f);
    unsigned r = 0x7FFFu + ((u >> 16) & 1u);
    return (ushort_t)((u + r) >> 16);
}

__global__ __launch_bounds__(256) void cvt_x_kernel(const float* __restrict__ x,
                                                    ushort_t* __restrict__ xb) {
    size_t i = ((size_t)blockIdx.x * 256 + threadIdx.x) * 4;
    float4 v = *reinterpret_cast<const float4*>(x + i);
    ushort4v o;
    o.x = f32_to_bf16_rne(v.x);
    o.y = f32_to_bf16_rne(v.y);
    o.z = f32_to_bf16_rne(v.z);
    o.w = f32_to_bf16_rne(v.w);
    *reinterpret_cast<ushort4v*>(xb + i) = o;
}

__global__ __launch_bounds__(256) void cvt_w_kernel(const float* __restrict__ w,
                                                    ushort_t* __restrict__ wb) {
    size_t i = ((size_t)blockIdx.x * 256 + threadIdx.x) * 4;
    float4 v = *reinterpret_cast<const float4*>(w + i);
    ushort4v o;
    o.x = (v.x >= 0.f) ? 0x3F80u : 0xBF80u;
    o.y = (v.y >= 0.f) ? 0x3F80u : 0xBF80u;
    o.z = (v.z >= 0.f) ? 0x3F80u : 0xBF80u;
    o.w = (v.w >= 0.f) ? 0x3F80u : 0xBF80u;
    *reinterpret_cast<ushort4v*>(wb + i) = o;
}

static __device__ __forceinline__ void gload_lds16(const void* g, void* s) {
    __builtin_amdgcn_global_load_lds(
        (const __attribute__((address_space(1))) void*)(g),
        (__attribute__((address_space(3))) void*)(s),
        16, 0, 0);
}

// LDS geometry: buf b at b*65536; A region +0 (32KB = 256 rows x 128B),
// B region +32768. Half h = rows h*128 = bytes [h*16384, +16384).
// Swizzle involution within region: P = L ^ (((L>>7)&7)<<4).

#define STAGE_A(bufbase, h, kt) do {                                        \
    char* _d = (bufbase) + (h)*16384 + w*1024;                              \
    gload_lds16(srcA0 + (size_t)(h)*1048576 + (size_t)(kt)*128, _d);        \
    gload_lds16(srcA1 + (size_t)(h)*1048576 + (size_t)(kt)*128, _d + 8192); \
} while (0)

#define STAGE_B(bufbase, h, kt) do {                                        \
    char* _d = (bufbase) + 32768 + (h)*16384 + w*1024;                      \
    gload_lds16(srcB0 + (size_t)(h)*1048576 + (size_t)(kt)*128, _d);        \
    gload_lds16(srcB1 + (size_t)(h)*1048576 + (size_t)(kt)*128, _d + 8192); \
} while (0)

// Per-kk fragment reads, issued in MFMA consumption order.
#define LDA_K(Abase, Mh, kk, areg) do {                                     \
    const int _sx = (kk) ? sxk1 : sxk0;                                     \
    _Pragma("unroll") for (int m = 0; m < 4; ++m)                           \
        areg[m*2+(kk)] = *(const bf16x8*)((Abase) + pbA + (Mh)*16384        \
                                          + m*2048 + _sx);                  \
} while (0)

#define LDB_K(Bbase, Nh, kk, breg) do {                                     \
    const int _sx = (kk) ? sxk1 : sxk0;                                     \
    _Pragma("unroll") for (int n = 0; n < 2; ++n)                           \
        breg[n*2+(kk)] = *(const bf16x8*)((Bbase) + pbB + (Nh)*16384        \
                                          + n*2048 + _sx);                  \
} while (0)

// kk-outer: 8 independent MFMAs between dependent accumulator reuses.
#define MM16(areg, breg, accq) do {                                         \
    __builtin_amdgcn_s_setprio(1);                                          \
    _Pragma("unroll") for (int kk = 0; kk < 2; ++kk)                        \
    _Pragma("unroll") for (int m = 0; m < 4; ++m)                           \
    _Pragma("unroll") for (int n = 0; n < 2; ++n)                           \
        accq[m][n] = __builtin_amdgcn_mfma_f32_16x16x32_bf16(               \
            areg[m*2+kk], breg[n*2+kk], accq[m][n], 0, 0, 0);               \
    __builtin_amdgcn_s_setprio(0);                                          \
} while (0)

#define BAR() __builtin_amdgcn_s_barrier()

// One K-tile = 4 phases. curb/othb static per instantiation.
// g: stage-(kt+2) guard. Boundary wait handled by caller.
#define TILE4(curb, othb, kt, g) do {                                       \
    char* Ab = (curb);                                                      \
    char* Bb = (curb) + 32768;                                              \
    /* phase 1: (Mh0,Nh0) */                                                \
    LDA_K(Ab, 0, 0, a); LDB_K(Bb, 0, 0, b0);                                \
    LDA_K(Ab, 0, 1, a); LDB_K(Bb, 0, 1, b0);                                \
    STAGE_B((othb), 1, (kt) + 1);                                           \
    BAR();                                                                  \
    MM16(a, b0, acc[0][0]);                                                 \
    BAR();                                                                  \
    /* phase 2: (Mh0,Nh1) */                                                \
    LDB_K(Bb, 1, 0, b1); LDB_K(Bb, 1, 1, b1);                               \
    if (g) STAGE_A((curb), 0, (kt) + 2);                                    \
    BAR();                                                                  \
    MM16(a, b1, acc[0][1]);                                                 \
    BAR();                                                                  \
    /* phase 3: (Mh1,Nh1) */                                                \
    LDA_K(Ab, 1, 0, a); LDA_K(Ab, 1, 1, a);                                 \
    if (g) STAGE_B((curb), 0, (kt) + 2);                                    \
    BAR();                                                                  \
    MM16(a, b1, acc[1][1]);                                                 \
    BAR();                                                                  \
    /* phase 4: (Mh1,Nh0) — regs from ph3/ph1, no ds_reads */               \
    if (g) STAGE_A((curb), 1, (kt) + 2);                                    \
    BAR();                                                                  \
    MM16(a, b0, acc[1][0]);                                                 \
} while (0)

__global__ __launch_bounds__(512, 2)
void bgemm8_kernel(const ushort_t* __restrict__ A, const ushort_t* __restrict__ Bm,
                   const float* __restrict__ bias, float* __restrict__ C) {
    __shared__ char lds[131072];

    const int t = threadIdx.x;
    const int w = t >> 6;          // wave 0..7
    const int l = t & 63;
    const int wr = w >> 2;         // 0..1 (M)
    const int wc = w & 3;          // 0..3 (N)

    // XCD swizzle: 512 blocks, 512 % 8 == 0 -> bijective
    const int bid = blockIdx.x;
    const int wg  = (bid & 7) * 64 + (bid >> 3);
    const int tn  = wg & 15;       // N tiles: 4096/256 = 16
    const int tm  = wg >> 4;       // M tiles: 8192/256 = 32

    // ---- staging: thread t, call j covers physical bytes [(j*512+t)*16,+16)
    // of a 16KB half-tile; invert swizzle for the global source.
    int srow[2], skb[2];
#pragma unroll
    for (int j = 0; j < 2; ++j) {
        int p = (j * 512 + t) * 16;
        int L = p ^ (((p >> 7) & 7) << 4);
        srow[j] = L >> 7;
        skb[j]  = L & 127;
    }
    const char* srcA0 = (const char*)A  + ((size_t)(tm * 256) + srow[0]) * KROW + skb[0];
    const char* srcA1 = (const char*)A  + ((size_t)(tm * 256) + srow[1]) * KROW + skb[1];
    const char* srcB0 = (const char*)Bm + ((size_t)(tn * 256) + srow[0]) * KROW + skb[0];
    const char* srcB1 = (const char*)Bm + ((size_t)(tn * 256) + srow[1]) * KROW + skb[1];

    // ---- fragment read addressing: logical col c = kk*64 + kh*16 bytes;
    // physical = c ^ ((row&7)<<4) with row&7 == l&7.
    const int lr = l & 15;
    const int kh = l >> 4;
    const int x7 = (l & 7) << 4;
    const int sxk0 = (kh * 16) ^ x7;
    const int sxk1 = (64 + kh * 16) ^ x7;
    const int pbA = (wr * 64 + lr) * 128;
    const int pbB = (wc * 32 + lr) * 128;

    char* const buf0 = lds;
    char* const buf1 = lds + 65536;

    // ---- prologue: tile0 -> buf0 (4 halves); tile1 A0,B0,A1 -> buf1
    STAGE_A(buf0, 0, 0); STAGE_B(buf0, 0, 0); STAGE_A(buf0, 1, 0); STAGE_B(buf0, 1, 0);
    STAGE_A(buf1, 0, 1); STAGE_B(buf1, 0, 1); STAGE_A(buf1, 1, 1);
    asm volatile("s_waitcnt vmcnt(6)" ::: "memory");
    BAR();

    f32x4 acc[2][2][4][2] = {};
    bf16x8 a[8], b0[4], b1[4];

#pragma unroll 1
    for (int kt = 0; kt < NKT; kt += 2) {
        const bool g = (kt < NKT - 2);   // stage-(+2) guard, uniform

        // ---- even tile kt: buf0 current, buf1 other
        TILE4(buf0, buf1, kt, g);
        if (g)  asm volatile("s_waitcnt vmcnt(6)" ::: "memory");
        else    asm volatile("s_waitcnt vmcnt(0)" ::: "memory");
        BAR();

        // ---- odd tile kt+1: buf1 current, buf0 other
        TILE4(buf1, buf0, kt + 1, g);
        if (g) asm volatile("s_waitcnt vmcnt(6)" ::: "memory");
        BAR();
    }

    // ---- epilogue: C/D layout col=lane&15, row=(lane>>4)*4+reg (verified)
    const int r0 = tm * 256 + wr * 64 + kh * 4;
    const int c0 = tn * 256 + wc * 32 + lr;
#pragma unroll
    for (int Mh = 0; Mh < 2; ++Mh)
#pragma unroll
    for (int Nh = 0; Nh < 2; ++Nh)
#pragma unroll
    for (int n = 0; n < 2; ++n) {
        const int col = c0 + Nh * 128 + n * 16;
        const float bs = (bias[col] >= 0.f) ? 1.f : -1.f;
#pragma unroll
        for (int m = 0; m < 4; ++m)
#pragma unroll
        for (int j = 0; j < 4; ++j) {
            const int row = r0 + Mh * 128 + m * 16 + j;
            C[(size_t)row * N_DIM + col] = acc[Mh][Nh][m][n][j] + bs;
        }
    }
}

extern "C" void kernel_launch(void* const* d_in, const int* in_sizes, int n_in,
                              void* d_out, int out_size, void* d_ws, size_t ws_size,
                              hipStream_t stream) {
    const float* x    = (const float*)d_in[0];
    const float* wgt  = (const float*)d_in[1];
    const float* bias = (const float*)d_in[2];
    float* out = (float*)d_out;

    ushort_t* xb = (ushort_t*)d_ws;                       // 64 MB
    ushort_t* wb = xb + (size_t)M_DIM * K_DIM;            // 32 MB

    cvt_x_kernel<<<(M_DIM * (size_t)K_DIM) / 4 / 256, 256, 0, stream>>>(x, xb);
    cvt_w_kernel<<<(N_DIM * (size_t)K_DIM) / 4 / 256, 256, 0, stream>>>(wgt, wb);

    dim3 grid((M_DIM / 256) * (N_DIM / 256));             // 32*16 = 512
    bgemm8_kernel<<<grid, 512, 0, stream>>>(xb, wb, bias, out);
}